// Round 1
// baseline (558.668 us; speedup 1.0000x reference)
//
#include <hip/hip_runtime.h>

// GCN layer: out = Ahat @ x @ W^T + bias, Ahat = D^-1/2 (A + I) D^-1/2
// Restructured: y = x @ W^T first (linear ops commute), then scatter edges
// directly into d_out which was initialized with self-loop + bias term.

__global__ void k_deg(const int* __restrict__ col, int* __restrict__ cnt, int E) {
    int e = blockIdx.x * blockDim.x + threadIdx.x;
    if (e < E) atomicAdd(&cnt[col[e]], 1);
}

__global__ void k_dinv(const int* __restrict__ cnt, float* __restrict__ dinv, int n) {
    int i = blockIdx.x * blockDim.x + threadIdx.x;
    if (i < n) dinv[i] = rsqrtf((float)(cnt[i] + 1));  // +1 self loop; always > 0
}

// y = x @ W^T ; x:[n,64], W:[64,64] row-major W[o][d]; 16 rows per block.
__global__ __launch_bounds__(256) void k_gemm(const float* __restrict__ x,
                                              const float* __restrict__ W,
                                              float* __restrict__ y, int n) {
    __shared__ float Wt[64 * 64];   // Wt[d*64 + o]  (transposed: lane-consecutive in o)
    __shared__ float xs[16 * 64];
    int t = threadIdx.x;
    // Stage W transposed into LDS (coalesced global float4 reads).
    for (int f = t * 4; f < 64 * 64; f += 256 * 4) {
        float4 w = *(const float4*)(W + f);
        int o = f >> 6, d = f & 63;          // 4 consecutive d within one o-row
        Wt[(d + 0) * 64 + o] = w.x;
        Wt[(d + 1) * 64 + o] = w.y;
        Wt[(d + 2) * 64 + o] = w.z;
        Wt[(d + 3) * 64 + o] = w.w;
    }
    // Stage 16 x-rows (1024 floats) as float4.
    long long base = (long long)blockIdx.x * 1024;
    long long total = (long long)n * 64;
    if (base + t * 4 + 3 < total) {
        float4 xv = *(const float4*)(x + base + t * 4);
        *(float4*)(xs + t * 4) = xv;
    }
    __syncthreads();

    int r  = t >> 4;            // local row 0..15
    int og = (t & 15) << 2;     // output group 0,4,...,60
    float a0 = 0.f, a1 = 0.f, a2 = 0.f, a3 = 0.f;
    #pragma unroll
    for (int d = 0; d < 64; ++d) {
        float xv = xs[r * 64 + d];                       // broadcast (free)
        float4 wv = *(const float4*)(Wt + d * 64 + og);  // b128, ~2-way max
        a0 += xv * wv.x; a1 += xv * wv.y; a2 += xv * wv.z; a3 += xv * wv.w;
    }
    int row = blockIdx.x * 16 + r;
    if (row < n) {
        float4 ov = make_float4(a0, a1, a2, a3);
        *(float4*)(y + (long long)row * 64 + og) = ov;
    }
}

// out[i][o] = dinv[i]^2 * y[i][o] + bias[o]   (full write: handles 0xAA poison)
__global__ void k_init(const float* __restrict__ y, const float* __restrict__ dinv,
                       const float* __restrict__ bias, float* __restrict__ out, int n) {
    int t = blockIdx.x * blockDim.x + threadIdx.x;   // one thread per 4 channels
    if (t >= n * 16) return;
    int i  = t >> 4;
    int o4 = (t & 15) << 2;
    float s = dinv[i];
    s = s * s;
    float4 yv = *(const float4*)(y + (long long)i * 64 + o4);
    float4 bv = *(const float4*)(bias + o4);
    float4 ov = make_float4(s * yv.x + bv.x, s * yv.y + bv.y,
                            s * yv.z + bv.z, s * yv.w + bv.w);
    *(float4*)(out + (long long)i * 64 + o4) = ov;
}

// One 64-lane group per edge; lane d handles channel d. Coalesced 256B bursts.
__global__ __launch_bounds__(256) void k_scatter(const int* __restrict__ row,
                                                 const int* __restrict__ col,
                                                 const float* __restrict__ y,
                                                 const float* __restrict__ dinv,
                                                 float* __restrict__ out, int E) {
    int e = blockIdx.x * 4 + (threadIdx.x >> 6);
    if (e >= E) return;
    int d = threadIdx.x & 63;
    int r = row[e], c = col[e];          // wave-uniform
    float w = dinv[r] * dinv[c];
    atomicAdd(out + (long long)c * 64 + d, w * y[(long long)r * 64 + d]);
}

extern "C" void kernel_launch(void* const* d_in, const int* in_sizes, int n_in,
                              void* d_out, int out_size, void* d_ws, size_t ws_size,
                              hipStream_t stream) {
    const float* x    = (const float*)d_in[0];
    const int*   ei   = (const int*)d_in[1];
    // d_in[2] = x0 (unused: use_init=False)
    const float* W    = (const float*)d_in[3];
    const float* bias = (const float*)d_in[4];
    float* out = (float*)d_out;

    int n = in_sizes[0] / 64;
    int E = in_sizes[1] / 2;
    const int* row = ei;        // source
    const int* col = ei + E;    // target

    char* ws = (char*)d_ws;
    int*   cnt  = (int*)ws;                               // n ints
    float* dinv = (float*)(ws + (size_t)n * 4);           // n floats
    float* y    = (float*)(ws + (size_t)n * 8);           // n*64 floats (16B-aligned)

    hipMemsetAsync(cnt, 0, (size_t)n * 4, stream);
    k_deg    <<<(E + 255) / 256, 256, 0, stream>>>(col, cnt, E);
    k_dinv   <<<(n + 255) / 256, 256, 0, stream>>>(cnt, dinv, n);
    k_gemm   <<<(n + 15) / 16,   256, 0, stream>>>(x, W, y, n);
    k_init   <<<(n * 16 + 255) / 256, 256, 0, stream>>>(y, dinv, bias, out, n);
    k_scatter<<<(E + 3) / 4,     256, 0, stream>>>(row, col, y, dinv, out, E);
}

// Round 2
// 402.615 us; speedup vs baseline: 1.3876x; 1.3876x over previous
//
#include <hip/hip_runtime.h>

// GCN layer: out = Ahat @ x @ W^T + bias, Ahat = D^-1/2 (A + I) D^-1/2
// y = x @ W^T first, then CSR-based gather-reduce per destination node
// (no float atomics). Self-loop + bias folded into the gather epilogue.

__global__ void k_deg(const int* __restrict__ col, int* __restrict__ cnt, int E) {
    int e = blockIdx.x * blockDim.x + threadIdx.x;
    if (e < E) atomicAdd(&cnt[col[e]], 1);
}

// Inclusive scan of 256-element tiles; per-block totals to bsum.
__global__ __launch_bounds__(256) void k_scanA(const int* __restrict__ cnt,
                                               int* __restrict__ incl,
                                               int* __restrict__ bsum, int n) {
    __shared__ int s[256];
    int i = blockIdx.x * 256 + threadIdx.x;
    int v = (i < n) ? cnt[i] : 0;
    s[threadIdx.x] = v;
    __syncthreads();
    for (int off = 1; off < 256; off <<= 1) {
        int t = (threadIdx.x >= off) ? s[threadIdx.x - off] : 0;
        __syncthreads();
        s[threadIdx.x] += t;
        __syncthreads();
    }
    if (i < n) incl[i] = s[threadIdx.x];
    if (threadIdx.x == 255) bsum[blockIdx.x] = s[255];
}

// Exclusive scan of block sums (nb <= 512), single block.
__global__ __launch_bounds__(512) void k_scanB(int* __restrict__ bsum, int nb) {
    __shared__ int s[512];
    int v = (threadIdx.x < nb) ? bsum[threadIdx.x] : 0;
    s[threadIdx.x] = v;
    __syncthreads();
    for (int off = 1; off < 512; off <<= 1) {
        int t = (threadIdx.x >= off) ? s[threadIdx.x - off] : 0;
        __syncthreads();
        s[threadIdx.x] += t;
        __syncthreads();
    }
    if (threadIdx.x < nb) bsum[threadIdx.x] = s[threadIdx.x] - v;  // exclusive
}

// rowptr/cursor = exclusive offsets; also dinv = rsqrt(deg+1).
__global__ void k_scanC(const int* __restrict__ cnt, const int* __restrict__ incl,
                        const int* __restrict__ bsum, int* __restrict__ rowptr,
                        int* __restrict__ cursor, float* __restrict__ dinv,
                        int n, int E) {
    int i = blockIdx.x * blockDim.x + threadIdx.x;
    if (i >= n) return;
    int ex = incl[i] - cnt[i] + bsum[i >> 8];
    rowptr[i] = ex;
    cursor[i] = ex;
    dinv[i] = rsqrtf((float)(cnt[i] + 1));
    if (i == n - 1) rowptr[n] = E;
}

// Place (src, dinv[src]) into dest-sorted CSR slots.
__global__ void k_fill(const int* __restrict__ row, const int* __restrict__ col,
                       const float* __restrict__ dinv, int* __restrict__ cursor,
                       int2* __restrict__ pairs, int E) {
    int e = blockIdx.x * blockDim.x + threadIdx.x;
    if (e >= E) return;
    int r = row[e], c = col[e];
    int pos = atomicAdd(&cursor[c], 1);
    pairs[pos] = make_int2(r, __float_as_int(dinv[r]));   // dinv: 400KB, L2-hot
}

// y = x @ W^T ; x:[n,64], W:[64,64] row-major W[o][d]; 16 rows per block.
__global__ __launch_bounds__(256) void k_gemm(const float* __restrict__ x,
                                              const float* __restrict__ W,
                                              float* __restrict__ y, int n) {
    __shared__ float Wt[64 * 64];   // Wt[d*64 + o]
    __shared__ float xs[16 * 64];
    int t = threadIdx.x;
    for (int f = t * 4; f < 64 * 64; f += 256 * 4) {
        float4 w = *(const float4*)(W + f);
        int o = f >> 6, d = f & 63;
        Wt[(d + 0) * 64 + o] = w.x;
        Wt[(d + 1) * 64 + o] = w.y;
        Wt[(d + 2) * 64 + o] = w.z;
        Wt[(d + 3) * 64 + o] = w.w;
    }
    long long base = (long long)blockIdx.x * 1024;
    long long total = (long long)n * 64;
    if (base + t * 4 + 3 < total) {
        float4 xv = *(const float4*)(x + base + t * 4);
        *(float4*)(xs + t * 4) = xv;
    }
    __syncthreads();

    int r  = t >> 4;
    int og = (t & 15) << 2;
    float a0 = 0.f, a1 = 0.f, a2 = 0.f, a3 = 0.f;
    #pragma unroll
    for (int d = 0; d < 64; ++d) {
        float xv = xs[r * 64 + d];
        float4 wv = *(const float4*)(Wt + d * 64 + og);
        a0 += xv * wv.x; a1 += xv * wv.y; a2 += xv * wv.z; a3 += xv * wv.w;
    }
    int rw = blockIdx.x * 16 + r;
    if (rw < n) {
        *(float4*)(y + (long long)rw * 64 + og) = make_float4(a0, a1, a2, a3);
    }
}

// One wave per destination node; lane d = channel d. Registers accumulate,
// single coalesced store. Self-loop + bias fused.
__global__ __launch_bounds__(256) void k_gather(const int* __restrict__ rowptr,
                                                const int2* __restrict__ pairs,
                                                const float* __restrict__ y,
                                                const float* __restrict__ dinv,
                                                const float* __restrict__ bias,
                                                float* __restrict__ out, int n) {
    int c = blockIdx.x * 4 + (threadIdx.x >> 6);
    if (c >= n) return;
    int d = threadIdx.x & 63;
    int start = rowptr[c], end = rowptr[c + 1];

    float acc = 0.f;
    for (int base = start; base < end; base += 64) {
        int j = base + d;                 // lane d loads the d-th edge of chunk
        int sid = 0; float w = 0.f;
        if (j < end) {
            int2 p = pairs[j];
            sid = p.x;
            w = __int_as_float(p.y);
        }
        int m = min(end - base, 64);
        #pragma unroll 4
        for (int k = 0; k < m; ++k) {
            int   r  = __shfl(sid, k);
            float wk = __shfl(w, k);
            acc += wk * y[(long long)r * 64 + d];
        }
    }
    float dc = dinv[c];
    float self = dc * dc * y[(long long)c * 64 + d];
    out[(long long)c * 64 + d] = dc * acc + self + bias[d];
}

extern "C" void kernel_launch(void* const* d_in, const int* in_sizes, int n_in,
                              void* d_out, int out_size, void* d_ws, size_t ws_size,
                              hipStream_t stream) {
    const float* x    = (const float*)d_in[0];
    const int*   ei   = (const int*)d_in[1];
    // d_in[2] = x0 (unused: use_init=False)
    const float* W    = (const float*)d_in[3];
    const float* bias = (const float*)d_in[4];
    float* out = (float*)d_out;

    int n = in_sizes[0] / 64;
    int E = in_sizes[1] / 2;
    const int* row = ei;        // source
    const int* col = ei + E;    // target

    // Workspace layout (16B-aligned chunks).
    char* ws = (char*)d_ws;
    size_t off = 0;
    auto alloc = [&](size_t bytes) { char* p = ws + off; off += (bytes + 15) & ~size_t(15); return p; };
    int*   cnt    = (int*)  alloc((size_t)n * 4);
    int*   incl   = (int*)  alloc((size_t)n * 4);
    int*   bsum   = (int*)  alloc(512 * 4);
    int*   rowptr = (int*)  alloc((size_t)(n + 1) * 4);
    int*   cursor = (int*)  alloc((size_t)n * 4);
    float* dinv   = (float*)alloc((size_t)n * 4);
    float* y      = (float*)alloc((size_t)n * 64 * 4);
    int2*  pairs  = (int2*) alloc((size_t)E * 8);

    int nbA = (n + 255) / 256;   // 391 for n=100k (fits k_scanB's 512)

    hipMemsetAsync(cnt, 0, (size_t)n * 4, stream);
    k_deg   <<<(E + 255) / 256, 256, 0, stream>>>(col, cnt, E);
    k_scanA <<<nbA, 256, 0, stream>>>(cnt, incl, bsum, n);
    k_scanB <<<1, 512, 0, stream>>>(bsum, nbA);
    k_scanC <<<nbA, 256, 0, stream>>>(cnt, incl, bsum, rowptr, cursor, dinv, n, E);
    k_fill  <<<(E + 255) / 256, 256, 0, stream>>>(row, col, dinv, cursor, pairs, E);
    k_gemm  <<<(n + 15) / 16, 256, 0, stream>>>(x, W, y, n);
    k_gather<<<(n + 3) / 4, 256, 0, stream>>>(rowptr, pairs, y, dinv, bias, out, n);
}